// Round 1
// 459.023 us; speedup vs baseline: 1.0002x; 1.0002x over previous
//
#include <hip/hip_runtime.h>
#include <hip/hip_fp16.h>

// DKVMN forward, v18 = R15 structure + lane-rebalanced state kernel.
//  Theory: dkvmn_state is VALU-issue-bound (VALUBusy 76%, Mfma 0, HBM 12%).
//  Old shape: 2048 blocks x 256 thr, VD=200 active of 256 -> wave 3 issues a
//  full 334-cyc stream for 8 real columns (lanes 200..255 clamp-duplicate
//  column 199). 22% of issued cycles were duplicated work.
//  New shape: BB*4 single-wave (64-thr) blocks. Roles 0..2 = dense heavy
//  waves (64 unique columns each, clamp removed). Role 3 = tail wave: the 8
//  columns v=192..199 spread 2-D (lane = grp*?; grp owns 4 slot-pairs of a
//  pair-padded 32-pair row, WHS 28->32 zero-padded), read reduced via
//  shfl_xor(8/16/32). Tail step ~100cyc vs 334. Per-batch issue work x0.82.
//  Single-wave blocks let the HW mix heavy/light across SIMDs dynamically.
//  k1 prep : EA {-e,a} f16 | Wt/Wh/Q1 | W1s pack | zero outputs 1..3.
//  k2 dkvmn_state: barrier-free, fdot2 read + hfma2 update, SGPR Wh pairs
//      (heavy) / dwordx4 Wh quads (tail), EA+W depth-2 prefetch, RD bf16.
//  k3 mlp_pred : MFMA 16x16x32 bf16 GEMM [B*S,224]@[224,64] + fused epilogue.
// Workspace: Wt 1MB | Q1 1MB | EA 8MB | W1s 32KB | Wh 0.64MB | RD 164MB.

#define NQ1   5001
#define NQA   10001
#define MEMN  50
#define KD    50
#define VD    200
#define FC    50
#define BB    2048
#define SS    200
#define EA_R  16
#define WHS   32       // Wh row stride in u32 (25 pairs + 7 zero pad, 128B)

#define EA_B   626     // ceil(10001/16)
#define WQ_B   1251    // ceil(5001/4)
#define PACK_B 8
#define PREP_G (EA_B + WQ_B + PACK_B)   // 1885 blocks

typedef unsigned int   u32;
typedef unsigned short u16;
typedef short    s8v __attribute__((ext_vector_type(8)));   // 8 bf16 (4 VGPRs)
typedef float    f4v __attribute__((ext_vector_type(4)));   // MFMA C/D
typedef _Float16 h2v __attribute__((ext_vector_type(2)));   // packed f16 pair
typedef u32      u4v __attribute__((ext_vector_type(4)));   // dwordx4

__device__ __forceinline__ float fast_sigmoid(float x) { return 1.f / (1.f + __expf(-x)); }
__device__ __forceinline__ float fast_tanh(float x) {
    float e2 = __expf(2.f * x);           // inf-safe
    return 1.f - 2.f / (e2 + 1.f);
}
__device__ __forceinline__ float bfu16_to_f(u16 u) {
    union { float f; u32 i; } x; x.i = ((u32)u) << 16; return x.f;
}
__device__ __forceinline__ u16 f_to_bfu16(float f) {   // RNE, finite inputs
    union { float f; u32 i; } x; x.f = f;
    return (u16)((x.i + 0x7fffu + ((x.i >> 16) & 1u)) >> 16);
}
__device__ __forceinline__ h2v u32_to_h2v(u32 u) {
    union { u32 i; h2v h; } x; x.i = u; return x.h;
}
__device__ __forceinline__ u16 f16bits(float f) {
    union { __half h; u16 u; } x; x.h = __float2half(f); return x.u;
}
__device__ __forceinline__ float h16_to_f(u16 u) {
    union { u16 u; __half h; } x; x.u = u; return __half2float(x.h);
}

// ---- merged prep: EA table | per-q tables | W1 pack | aux-output zeroing ----
__global__ __launch_bounds__(256) void prep(
        const float* __restrict__ qemb, const float* __restrict__ km,
        const float* __restrict__ w1,   const float* __restrict__ b1,
        const float* __restrict__ qaemb,
        const float* __restrict__ ew,   const float* __restrict__ ebias,
        const float* __restrict__ aw,   const float* __restrict__ abias,
        float* __restrict__ Wt, u32* __restrict__ Wh, float* __restrict__ Q1,
        u32* __restrict__ EA, u16* __restrict__ W1s,
        float* __restrict__ out_aux) {
    const int tid = threadIdx.x;
    const int blk = blockIdx.x;

    // every block zeroes its slice of outputs 1..3 (replaces hipMemsetAsync)
    for (size_t i = (size_t)blk * 256 + tid; i < 3ull * BB * SS;
         i += (size_t)PREP_G * 256)
        out_aux[i] = 0.f;

    __shared__ float smem[VD * EA_R];             // 12.8 KB (EA role); WQ uses 256

    if (blk < EA_B) {
        // ---------------- EA role: {-e, a} packed f16 ----------------
        const int r0 = blk * EA_R;
        if (tid < VD) {
            #pragma unroll
            for (int r = 0; r < EA_R; ++r) {
                int row = r0 + r;
                smem[tid * EA_R + r] = (row < NQA) ? qaemb[(size_t)row * VD + tid] : 0.f;
            }
        }
        __syncthreads();
        if (tid >= VD) return;

        float accE[EA_R], accA[EA_R];
        #pragma unroll
        for (int r = 0; r < EA_R; ++r) { accE[r] = 0.f; accA[r] = 0.f; }
        for (int k = 0; k < VD; ++k) {
            float we = ew[k * VD + tid];
            float wa = aw[k * VD + tid];
            #pragma unroll
            for (int r = 0; r < EA_R; ++r) {
                float qv = smem[k * EA_R + r];
                accE[r] = fmaf(qv, we, accE[r]);
                accA[r] = fmaf(qv, wa, accA[r]);
            }
        }
        float be = ebias[tid], ba = abias[tid];
        #pragma unroll
        for (int r = 0; r < EA_R; ++r) {
            int row = r0 + r;
            if (row < NQA) {
                u16 ne16 = f16bits(-fast_sigmoid(accE[r] + be));   // -e
                u16 a16  = f16bits(fast_tanh(accA[r] + ba));       //  a
                EA[(size_t)row * VD + tid] = (u32)ne16 | ((u32)a16 << 16);
            }
        }
    } else if (blk < EA_B + WQ_B) {
        // ---------------- WQ role (== proven build_wq, 4 q/block) ----------------
        const int lane = tid & 63;
        const int wv   = tid >> 6;
        const int q    = (blk - EA_B) * 4 + wv;
        const bool qok = q < NQ1;
        float* qrow = smem + wv * 64;             // 50 used per wave
        if (qok && lane < KD) qrow[lane] = qemb[q * KD + lane];
        __syncthreads();
        if (!qok) return;

        float s = -1e30f;
        if (lane < MEMN) {
            s = 0.f;
            #pragma unroll
            for (int k = 0; k < KD; ++k) s = fmaf(qrow[k], km[lane * KD + k], s);
        }
        float mx = s;
        #pragma unroll
        for (int off = 32; off >= 1; off >>= 1) mx = fmaxf(mx, __shfl_xor(mx, off, 64));
        float e = (lane < MEMN) ? __expf(s - mx) : 0.f;
        float sum = e;
        #pragma unroll
        for (int off = 32; off >= 1; off >>= 1) sum += __shfl_xor(sum, off, 64);
        float wv_ = (lane < MEMN) ? (e / sum) : 0.f;
        if (lane < MEMN) Wt[q * MEMN + lane] = wv_;

        // f16-pair row: lane i<25 packs (w[2i], w[2i+1]); pairs 25..31 zero
        float plo = __shfl(wv_, 2 * (lane & 31), 64);
        float phi = __shfl(wv_, 2 * (lane & 31) + 1, 64);
        if (lane < 25) {
            Wh[q * WHS + lane] = (u32)f16bits(plo) | ((u32)f16bits(phi) << 16);
        } else if (lane < WHS) {
            Wh[q * WHS + lane] = 0;
        }

        if (lane < FC) {
            float h = b1[lane];
            #pragma unroll
            for (int k = 0; k < KD; ++k)
                h = fmaf(qrow[k], w1[(VD + k) * FC + lane], h);
            Q1[q * FC + lane] = h;
        }
    } else {
        // ---------------- pack role (== proven pack_w1) ----------------
        for (int idx = (blk - EA_B - WQ_B) * 256 + tid; idx < 4 * 7 * 64 * 8;
             idx += PACK_B * 256) {
            int j    = idx & 7;
            int lane = (idx >> 3) & 63;
            int kt   = (idx >> 9) % 7;
            int nt   = idx / 3584;
            int k = kt * 32 + ((lane >> 4) << 3) + j;
            int n = nt * 16 + (lane & 15);
            float v = (k < VD && n < FC) ? w1[k * FC + n] : 0.f;
            W1s[idx] = f_to_bfu16(v);
        }
    }
}

// ---- recurrence: BB*4 single-wave blocks ----
//  role 0..2 : 64 dense columns each (v = role*64 + lane), proven heavy loop
//  role 3    : tail columns v=192..199 spread 2-D: lane=(grp,v8), grp owns
//              4 slot-pairs of the 32-pair zero-padded Wh row; read reduced
//              with shfl_xor(8/16/32); ~100cyc/step vs 334.
__global__ __launch_bounds__(64) void dkvmn_state(
        const int* __restrict__ qd, const int* __restrict__ qad,
        const u32* __restrict__ Wh, const u32* __restrict__ EA,
        const float* __restrict__ ivm, u16* __restrict__ READ) {
    const int tid  = threadIdx.x;          // 0..63
    const int blk  = blockIdx.x;
    const int b    = blk >> 2;
    const int role = blk & 3;
    const int base = b * SS;

    if (role < 3) {
        // ---------------- heavy wave: 64 unique columns ----------------
        const int v = role * 64 + tid;     // < 192, every lane unique

        h2v mv[25];                        // pair i = slots (2i, 2i+1)
        #pragma unroll
        for (int i = 0; i < 25; ++i) {
            mv[i].x = (_Float16)ivm[(2 * i) * VD + v];
            mv[i].y = (_Float16)ivm[(2 * i + 1) * VD + v];
        }

        int q_c = __builtin_amdgcn_readfirstlane(qd[base]);
        int q_n = __builtin_amdgcn_readfirstlane(qd[base + 1]);
        int qa0 = __builtin_amdgcn_readfirstlane(qad[base]);
        int qa1 = __builtin_amdgcn_readfirstlane(qad[base + 1]);
        u32 ea_c = EA[(size_t)qa0 * VD + v];
        u32 ea_n = EA[(size_t)qa1 * VD + v];

        for (int t = 0; t < SS; ++t) {
            // prefetch step t+2 (clamped index; duplicate load harmless)
            int tn = t + 2; tn = (tn < SS) ? tn : (SS - 1);
            int q_nn  = __builtin_amdgcn_readfirstlane(qd[base + tn]);
            int qa_nn = __builtin_amdgcn_readfirstlane(qad[base + tn]);
            u32 ea_nn = EA[(size_t)qa_nn * VD + v];

            const u32* wrow = Wh + q_c * WHS;        // uniform -> s_load clause
            // ea_c = {-e (lo f16), a (hi f16)}; broadcast halves via v_perm
            h2v nev2 = u32_to_h2v(__builtin_amdgcn_perm(ea_c, ea_c, 0x01000100u));
            h2v av2  = u32_to_h2v(__builtin_amdgcn_perm(ea_c, ea_c, 0x03020302u));

            float rdA = 0.f, rdB = 0.f;
            #pragma unroll
            for (int i = 0; i < 25; i += 2) {        // 13 iters (i=24 single)
                h2v w0 = u32_to_h2v(wrow[i]);
#if __has_builtin(__builtin_amdgcn_fdot2)
                rdA = __builtin_amdgcn_fdot2(w0, mv[i], rdA, false);
#else
                rdA = fmaf((float)w0.x, (float)mv[i].x,
                      fmaf((float)w0.y, (float)mv[i].y, rdA));
#endif
                mv[i] = __builtin_elementwise_fma(
                    w0, __builtin_elementwise_fma(nev2, mv[i], av2), mv[i]);
                if (i + 1 < 25) {
                    h2v w1p = u32_to_h2v(wrow[i + 1]);
#if __has_builtin(__builtin_amdgcn_fdot2)
                    rdB = __builtin_amdgcn_fdot2(w1p, mv[i + 1], rdB, false);
#else
                    rdB = fmaf((float)w1p.x, (float)mv[i + 1].x,
                          fmaf((float)w1p.y, (float)mv[i + 1].y, rdB));
#endif
                    mv[i + 1] = __builtin_elementwise_fma(
                        w1p, __builtin_elementwise_fma(nev2, mv[i + 1], av2), mv[i + 1]);
                }
            }
            READ[(size_t)(base + t) * VD + v] = f_to_bfu16(rdA + rdB);
            q_c = q_n; q_n = q_nn; ea_c = ea_n; ea_n = ea_nn;
        }
    } else {
        // ---------------- tail wave: v = 192..199, 8 slot-groups ----------------
        const int v8  = tid & 7;
        const int grp = tid >> 3;          // owns pairs grp*4 .. grp*4+3
        const int v   = 192 + v8;

        h2v mv4[4];
        #pragma unroll
        for (int j = 0; j < 4; ++j) {
            int p = grp * 4 + j;
            if (p < 25) {
                mv4[j].x = (_Float16)ivm[(2 * p) * VD + v];
                mv4[j].y = (_Float16)ivm[(2 * p + 1) * VD + v];
            } else {                       // padded pairs: w=0 keeps them 0
                mv4[j].x = (_Float16)0.f;
                mv4[j].y = (_Float16)0.f;
            }
        }

        int q_c = __builtin_amdgcn_readfirstlane(qd[base]);
        int q_n = __builtin_amdgcn_readfirstlane(qd[base + 1]);
        int qa0 = __builtin_amdgcn_readfirstlane(qad[base]);
        int qa1 = __builtin_amdgcn_readfirstlane(qad[base + 1]);
        u32 ea_c = EA[(size_t)qa0 * VD + v];
        u32 ea_n = EA[(size_t)qa1 * VD + v];
        u4v wq_c = *(const u4v*)(Wh + (size_t)q_c * WHS + grp * 4);
        u4v wq_n = *(const u4v*)(Wh + (size_t)q_n * WHS + grp * 4);

        for (int t = 0; t < SS; ++t) {
            int tn = t + 2; tn = (tn < SS) ? tn : (SS - 1);
            int q_nn  = __builtin_amdgcn_readfirstlane(qd[base + tn]);
            int qa_nn = __builtin_amdgcn_readfirstlane(qad[base + tn]);
            u32 ea_nn = EA[(size_t)qa_nn * VD + v];
            u4v wq_nn = *(const u4v*)(Wh + (size_t)q_nn * WHS + grp * 4);

            h2v nev2 = u32_to_h2v(__builtin_amdgcn_perm(ea_c, ea_c, 0x01000100u));
            h2v av2  = u32_to_h2v(__builtin_amdgcn_perm(ea_c, ea_c, 0x03020302u));

            float rd = 0.f;
            #pragma unroll
            for (int j = 0; j < 4; ++j) {
                h2v w2 = u32_to_h2v(wq_c[j]);
#if __has_builtin(__builtin_amdgcn_fdot2)
                rd = __builtin_amdgcn_fdot2(w2, mv4[j], rd, false);
#else
                rd = fmaf((float)w2.x, (float)mv4[j].x,
                     fmaf((float)w2.y, (float)mv4[j].y, rd));
#endif
                mv4[j] = __builtin_elementwise_fma(
                    w2, __builtin_elementwise_fma(nev2, mv4[j], av2), mv4[j]);
            }
            // reduce over the 8 slot-groups (lane stride 8)
            rd += __shfl_xor(rd, 8, 64);
            rd += __shfl_xor(rd, 16, 64);
            rd += __shfl_xor(rd, 32, 64);
            if (grp == 0)
                READ[(size_t)(base + t) * VD + v] = f_to_bfu16(rd);

            q_c = q_n; q_n = q_nn; ea_c = ea_n; ea_n = ea_nn;
            wq_c = wq_n; wq_n = wq_nn;
        }
    }
}

// ---- prediction MLP via MFMA: per wave one 16-row strip, K=224, N=64 ----
__global__ __launch_bounds__(256) void mlp_pred(
        const u16* __restrict__ RD, const int* __restrict__ qd,
        const float* __restrict__ Q1tab, const u16* __restrict__ W1s,
        const float* __restrict__ w2, const float* __restrict__ b2,
        float* __restrict__ out) {
    const int tid  = threadIdx.x;
    const int lane = tid & 63;
    const int wv   = tid >> 6;
    const int strip = blockIdx.x * 4 + wv;
    const int row0  = strip * 16;

    const int mrow = lane & 15;        // A row within strip / C-D col (feature)
    const int quad = lane >> 4;

    s8v a[7];
    {
        const u16* arow = RD + (size_t)(row0 + mrow) * VD + quad * 8;
        #pragma unroll
        for (int kt = 0; kt < 7; ++kt)
            a[kt] = *(const s8v*)(arow + kt * 32);   // k>=200 garbage * B=0
    }

    const float b2f = b2[0];
    float pf[4] = {0.f, 0.f, 0.f, 0.f};

    #pragma unroll
    for (int nt = 0; nt < 4; ++nt) {
        s8v bfr[7];
        #pragma unroll
        for (int kt = 0; kt < 7; ++kt)
            bfr[kt] = *(const s8v*)(W1s + (((nt * 7 + kt) * 64) + lane) * 8);

        f4v acc = {0.f, 0.f, 0.f, 0.f};
        #pragma unroll
        for (int kt = 0; kt < 7; ++kt)
            acc = __builtin_amdgcn_mfma_f32_16x16x32_bf16(a[kt], bfr[kt], acc, 0, 0, 0);

        const int f = nt * 16 + mrow;                  // output feature col
        const float w2f = (f < FC) ? w2[f] : 0.f;
        #pragma unroll
        for (int r = 0; r < 4; ++r) {
            int row = row0 + quad * 4 + r;
            float h = acc[r] + Q1tab[qd[row] * FC + f];
            pf[r] = fmaf(fast_tanh(h), w2f, pf[r]);
        }
    }

    #pragma unroll
    for (int r = 0; r < 4; ++r) {
        float s = pf[r];
        s += __shfl_xor(s, 1, 64);
        s += __shfl_xor(s, 2, 64);
        s += __shfl_xor(s, 4, 64);
        s += __shfl_xor(s, 8, 64);
        if (mrow == 0)
            out[row0 + quad * 4 + r] = fast_sigmoid(s + b2f);
    }
}

// ---- fallback (barrier version, f32) if workspace too small ----
__global__ void dkvmn_main(const int* __restrict__ qd, const int* __restrict__ qad,
                           const float* __restrict__ Wtab, const float* __restrict__ Q1tab,
                           const u32* __restrict__ EA,
                           const float* __restrict__ ivm,
                           const float* __restrict__ w1,
                           const float* __restrict__ w2,
                           const float* __restrict__ b2,
                           float* __restrict__ out) {
    const int tid  = threadIdx.x;
    const int b    = blockIdx.x;
    const int v    = tid;
    const int lane = tid & 63;
    const int wv   = tid >> 6;

    __shared__ alignas(16) float read_lds[4 * 52];
    __shared__ alignas(16) float part_lds[4 * 52];

    float mv[MEMN];
    if (v < VD) {
        #pragma unroll
        for (int m = 0; m < MEMN; ++m) mv[m] = ivm[m * VD + v];
    }
    float w1r[50];
    if (lane < FC) {
        #pragma unroll
        for (int i = 0; i < 50; ++i) w1r[i] = w1[(wv * 50 + i) * FC + lane];
    } else {
        #pragma unroll
        for (int i = 0; i < 50; ++i) w1r[i] = 0.f;
    }
    const float w2f = (tid < FC) ? w2[tid] : 0.f;
    const float b2f = b2[0];

    const int* qrow_i  = qd  + b * SS;
    const int* qarow_i = qad + b * SS;
    const int jchunk = v / 50;
    const int wslot  = jchunk * 52 + (v - jchunk * 50);

    for (int t = 0; t < SS; ++t) {
        const int q  = __builtin_amdgcn_readfirstlane(qrow_i[t]);
        const int qa = __builtin_amdgcn_readfirstlane(qarow_i[t]);
        const float* wrow = Wtab + q * MEMN;

        u32 ea = 0;
        if (v < VD) ea = EA[(size_t)qa * VD + v];
        float ne = h16_to_f((u16)(ea & 0xffffu));   // -e
        float av = h16_to_f((u16)(ea >> 16));       //  a

        if (v < VD) {
            float rd0 = 0.f, rd1 = 0.f;
            #pragma unroll
            for (int m = 0; m < MEMN; m += 2) {
                float wm0 = wrow[m], wm1 = wrow[m + 1];
                rd0 = fmaf(wm0, mv[m], rd0);
                mv[m] = fmaf(wm0, fmaf(ne, mv[m], av), mv[m]);
                rd1 = fmaf(wm1, mv[m + 1], rd1);
                mv[m + 1] = fmaf(wm1, fmaf(ne, mv[m + 1], av), mv[m + 1]);
            }
            read_lds[wslot] = rd0 + rd1;
        }
        __syncthreads();

        float part = 0.f;
        {
            const float* rlc = read_lds + wv * 52;
            #pragma unroll
            for (int i = 0; i < 48; i += 4) {
                float4 x = *(const float4*)(rlc + i);
                part = fmaf(x.x, w1r[i],     part);
                part = fmaf(x.y, w1r[i + 1], part);
                part = fmaf(x.z, w1r[i + 2], part);
                part = fmaf(x.w, w1r[i + 3], part);
            }
            part = fmaf(rlc[48], w1r[48], part);
            part = fmaf(rlc[49], w1r[49], part);
        }
        if (lane < FC) part_lds[wv * 52 + lane] = part;
        __syncthreads();

        if (wv == 0) {
            float pf = 0.f;
            if (lane < FC) {
                float h = part_lds[lane] + part_lds[52 + lane] +
                          part_lds[104 + lane] + part_lds[156 + lane] +
                          Q1tab[q * FC + lane];
                pf = fast_tanh(h) * w2f;
            }
            #pragma unroll
            for (int off = 32; off >= 1; off >>= 1) pf += __shfl_xor(pf, off, 64);
            if (lane == 0) out[b * SS + t] = fast_sigmoid(pf + b2f);
        }
    }
}

extern "C" void kernel_launch(void* const* d_in, const int* in_sizes, int n_in,
                              void* d_out, int out_size, void* d_ws, size_t ws_size,
                              hipStream_t stream) {
    const int* qd  = (const int*)d_in[0];
    const int* qad = (const int*)d_in[1];
    const float* qemb  = (const float*)d_in[2];
    const float* qaemb = (const float*)d_in[3];
    const float* km    = (const float*)d_in[4];
    const float* ivm   = (const float*)d_in[5];
    const float* ew    = (const float*)d_in[6];
    const float* eb    = (const float*)d_in[7];
    const float* aw    = (const float*)d_in[8];
    const float* ab    = (const float*)d_in[9];
    const float* w1    = (const float*)d_in[10];
    const float* b1    = (const float*)d_in[11];
    const float* w2    = (const float*)d_in[12];
    const float* b2    = (const float*)d_in[13];
    float* out = (float*)d_out;
    (void)in_sizes; (void)n_in; (void)out_size;

    char* ws = (char*)d_ws;
    float* Wt  = (float*)(ws);                       // 1,000,200 -> pad 1,000,448
    float* Q1  = (float*)(ws + 1000448);             // 1,000,200 -> pad 1,000,448
    u32*   EA  = (u32*)  (ws + 2000896);             // 8,000,800 -> pad 8,001,024
    u16*   W1s = (u16*)  (ws + 10001920);            // 28,672    -> pad 32,768
    u32*   Wh  = (u32*)  (ws + 10034688);            // 640,128   -> pad 640,512
    u16*   RD  = (u16*)  (ws + 10675200);            // 163,840,000
    const size_t need = 10675200ull + 163840000ull + 512ull;

    // prep: EA + Wt/Wh/Q1 + W1s + zero outputs 1..3 (one dispatch)
    prep<<<PREP_G, 256, 0, stream>>>(qemb, km, w1, b1, qaemb, ew, eb, aw, ab,
                                     Wt, Wh, Q1, EA, W1s, out + (size_t)BB * SS);

    if (ws_size >= need) {
        dkvmn_state<<<BB * 4, 64, 0, stream>>>(qd, qad, Wh, EA, ivm, RD);
        mlp_pred<<<(BB * SS) / 64, 256, 0, stream>>>(RD, qd, Q1, W1s, w2, b2, out);
    } else {
        dkvmn_main<<<BB, 256, 0, stream>>>(qd, qad, Wt, Q1, EA, ivm, w1, w2, b2, out);
    }
}

// Round 2
// 434.002 us; speedup vs baseline: 1.0578x; 1.0577x over previous
//
#include <hip/hip_runtime.h>
#include <hip/hip_fp16.h>

// DKVMN forward, v19 = v18 + Wh SGPR depth-1 prefetch + 2-wave blocks.
//  R1 evidence: lane-rebalance cut issue (VALUBusy 76->64%) but dur pinned at
//  326us in BOTH shapes. Fit: wall = issue + nWaves*S with S~155cyc/wave-step
//  in both configs -> a serialized per-step stall, prime suspect the per-step
//  Wh s_load clause (random 128B row of 640KB table, always misses sK$,
//  lgkmcnt wait heads every step's compute). Tail wave (VMEM w prefetch) is
//  immune by construction.
//  Fix 1: heavy waves double-buffer the Wh row in SGPRs, issuing the s_load
//         clause one step early (t-loop unrolled x2, zero VALU cost).
//  Fix 2: 128-thr 2-wave blocks (roles {0,1},{2,tail}) -> 16 wg/CU -> full
//         32 waves/CU residency in one round (1-wave blocks capped at ~16).
//  Math is bit-identical to v18 (same op order, f16 state, fdot2+hfma2).
//  k1 prep : EA {-e,a} f16 | Wt/Wh/Q1 | W1s pack | zero outputs 1..3.
//  k3 mlp_pred : MFMA 16x16x32 bf16 GEMM [B*S,224]@[224,64] + fused epilogue.
// Workspace: Wt 1MB | Q1 1MB | EA 8MB | W1s 32KB | Wh 0.64MB | RD 164MB.

#define NQ1   5001
#define NQA   10001
#define MEMN  50
#define KD    50
#define VD    200
#define FC    50
#define BB    2048
#define SS    200
#define EA_R  16
#define WHS   32       // Wh row stride in u32 (25 pairs + 7 zero pad, 128B)

#define EA_B   626     // ceil(10001/16)
#define WQ_B   1251    // ceil(5001/4)
#define PACK_B 8
#define PREP_G (EA_B + WQ_B + PACK_B)   // 1885 blocks

typedef unsigned int   u32;
typedef unsigned short u16;
typedef short    s8v __attribute__((ext_vector_type(8)));   // 8 bf16 (4 VGPRs)
typedef float    f4v __attribute__((ext_vector_type(4)));   // MFMA C/D
typedef _Float16 h2v __attribute__((ext_vector_type(2)));   // packed f16 pair
typedef u32      u4v __attribute__((ext_vector_type(4)));   // dwordx4

__device__ __forceinline__ float fast_sigmoid(float x) { return 1.f / (1.f + __expf(-x)); }
__device__ __forceinline__ float fast_tanh(float x) {
    float e2 = __expf(2.f * x);           // inf-safe
    return 1.f - 2.f / (e2 + 1.f);
}
__device__ __forceinline__ float bfu16_to_f(u16 u) {
    union { float f; u32 i; } x; x.i = ((u32)u) << 16; return x.f;
}
__device__ __forceinline__ u16 f_to_bfu16(float f) {   // RNE, finite inputs
    union { float f; u32 i; } x; x.f = f;
    return (u16)((x.i + 0x7fffu + ((x.i >> 16) & 1u)) >> 16);
}
__device__ __forceinline__ h2v u32_to_h2v(u32 u) {
    union { u32 i; h2v h; } x; x.i = u; return x.h;
}
__device__ __forceinline__ u16 f16bits(float f) {
    union { __half h; u16 u; } x; x.h = __float2half(f); return x.u;
}
__device__ __forceinline__ float h16_to_f(u16 u) {
    union { u16 u; __half h; } x; x.u = u; return __half2float(x.h);
}

// ---- merged prep: EA table | per-q tables | W1 pack | aux-output zeroing ----
__global__ __launch_bounds__(256) void prep(
        const float* __restrict__ qemb, const float* __restrict__ km,
        const float* __restrict__ w1,   const float* __restrict__ b1,
        const float* __restrict__ qaemb,
        const float* __restrict__ ew,   const float* __restrict__ ebias,
        const float* __restrict__ aw,   const float* __restrict__ abias,
        float* __restrict__ Wt, u32* __restrict__ Wh, float* __restrict__ Q1,
        u32* __restrict__ EA, u16* __restrict__ W1s,
        float* __restrict__ out_aux) {
    const int tid = threadIdx.x;
    const int blk = blockIdx.x;

    // every block zeroes its slice of outputs 1..3 (replaces hipMemsetAsync)
    for (size_t i = (size_t)blk * 256 + tid; i < 3ull * BB * SS;
         i += (size_t)PREP_G * 256)
        out_aux[i] = 0.f;

    __shared__ float smem[VD * EA_R];             // 12.8 KB (EA role); WQ uses 256

    if (blk < EA_B) {
        // ---------------- EA role: {-e, a} packed f16 ----------------
        const int r0 = blk * EA_R;
        if (tid < VD) {
            #pragma unroll
            for (int r = 0; r < EA_R; ++r) {
                int row = r0 + r;
                smem[tid * EA_R + r] = (row < NQA) ? qaemb[(size_t)row * VD + tid] : 0.f;
            }
        }
        __syncthreads();
        if (tid >= VD) return;

        float accE[EA_R], accA[EA_R];
        #pragma unroll
        for (int r = 0; r < EA_R; ++r) { accE[r] = 0.f; accA[r] = 0.f; }
        for (int k = 0; k < VD; ++k) {
            float we = ew[k * VD + tid];
            float wa = aw[k * VD + tid];
            #pragma unroll
            for (int r = 0; r < EA_R; ++r) {
                float qv = smem[k * EA_R + r];
                accE[r] = fmaf(qv, we, accE[r]);
                accA[r] = fmaf(qv, wa, accA[r]);
            }
        }
        float be = ebias[tid], ba = abias[tid];
        #pragma unroll
        for (int r = 0; r < EA_R; ++r) {
            int row = r0 + r;
            if (row < NQA) {
                u16 ne16 = f16bits(-fast_sigmoid(accE[r] + be));   // -e
                u16 a16  = f16bits(fast_tanh(accA[r] + ba));       //  a
                EA[(size_t)row * VD + tid] = (u32)ne16 | ((u32)a16 << 16);
            }
        }
    } else if (blk < EA_B + WQ_B) {
        // ---------------- WQ role (== proven build_wq, 4 q/block) ----------------
        const int lane = tid & 63;
        const int wv   = tid >> 6;
        const int q    = (blk - EA_B) * 4 + wv;
        const bool qok = q < NQ1;
        float* qrow = smem + wv * 64;             // 50 used per wave
        if (qok && lane < KD) qrow[lane] = qemb[q * KD + lane];
        __syncthreads();
        if (!qok) return;

        float s = -1e30f;
        if (lane < MEMN) {
            s = 0.f;
            #pragma unroll
            for (int k = 0; k < KD; ++k) s = fmaf(qrow[k], km[lane * KD + k], s);
        }
        float mx = s;
        #pragma unroll
        for (int off = 32; off >= 1; off >>= 1) mx = fmaxf(mx, __shfl_xor(mx, off, 64));
        float e = (lane < MEMN) ? __expf(s - mx) : 0.f;
        float sum = e;
        #pragma unroll
        for (int off = 32; off >= 1; off >>= 1) sum += __shfl_xor(sum, off, 64);
        float wv_ = (lane < MEMN) ? (e / sum) : 0.f;
        if (lane < MEMN) Wt[q * MEMN + lane] = wv_;

        // f16-pair row: lane i<25 packs (w[2i], w[2i+1]); pairs 25..31 zero
        float plo = __shfl(wv_, 2 * (lane & 31), 64);
        float phi = __shfl(wv_, 2 * (lane & 31) + 1, 64);
        if (lane < 25) {
            Wh[q * WHS + lane] = (u32)f16bits(plo) | ((u32)f16bits(phi) << 16);
        } else if (lane < WHS) {
            Wh[q * WHS + lane] = 0;
        }

        if (lane < FC) {
            float h = b1[lane];
            #pragma unroll
            for (int k = 0; k < KD; ++k)
                h = fmaf(qrow[k], w1[(VD + k) * FC + lane], h);
            Q1[q * FC + lane] = h;
        }
    } else {
        // ---------------- pack role (== proven pack_w1) ----------------
        for (int idx = (blk - EA_B - WQ_B) * 256 + tid; idx < 4 * 7 * 64 * 8;
             idx += PACK_B * 256) {
            int j    = idx & 7;
            int lane = (idx >> 3) & 63;
            int kt   = (idx >> 9) % 7;
            int nt   = idx / 3584;
            int k = kt * 32 + ((lane >> 4) << 3) + j;
            int n = nt * 16 + (lane & 15);
            float v = (k < VD && n < FC) ? w1[k * FC + n] : 0.f;
            W1s[idx] = f_to_bfu16(v);
        }
    }
}

// one recurrence step for 64 dense columns; w row lives in SGPRs
__device__ __forceinline__ void state_step(const u32 (&w)[25], u32 ea,
                                           h2v (&mv)[25], float& rdA, float& rdB) {
    // ea = {-e (lo f16), a (hi f16)}; broadcast halves via v_perm
    h2v nev2 = u32_to_h2v(__builtin_amdgcn_perm(ea, ea, 0x01000100u));
    h2v av2  = u32_to_h2v(__builtin_amdgcn_perm(ea, ea, 0x03020302u));
    rdA = 0.f; rdB = 0.f;
    #pragma unroll
    for (int i = 0; i < 25; i += 2) {        // 13 iters (i=24 single)
        h2v w0 = u32_to_h2v(w[i]);
#if __has_builtin(__builtin_amdgcn_fdot2)
        rdA = __builtin_amdgcn_fdot2(w0, mv[i], rdA, false);
#else
        rdA = fmaf((float)w0.x, (float)mv[i].x,
              fmaf((float)w0.y, (float)mv[i].y, rdA));
#endif
        mv[i] = __builtin_elementwise_fma(
            w0, __builtin_elementwise_fma(nev2, mv[i], av2), mv[i]);
        if (i + 1 < 25) {
            h2v w1p = u32_to_h2v(w[i + 1]);
#if __has_builtin(__builtin_amdgcn_fdot2)
            rdB = __builtin_amdgcn_fdot2(w1p, mv[i + 1], rdB, false);
#else
            rdB = fmaf((float)w1p.x, (float)mv[i + 1].x,
                  fmaf((float)w1p.y, (float)mv[i + 1].y, rdB));
#endif
            mv[i + 1] = __builtin_elementwise_fma(
                w1p, __builtin_elementwise_fma(nev2, mv[i + 1], av2), mv[i + 1]);
        }
    }
}

// ---- recurrence: BB*2 two-wave blocks ----
//  blk even -> roles {0,1}; blk odd -> roles {2, tail}; b = blk>>1.
//  heavy role r: 64 dense columns v = r*64+lane; Wh row double-buffered in
//  SGPRs with the s_load clause issued one step early (t-loop unrolled x2).
//  tail: v=192..199 spread 2-D (grp owns 4 slot-pairs), VMEM w prefetch.
__global__ __launch_bounds__(128) void dkvmn_state(
        const int* __restrict__ qd, const int* __restrict__ qad,
        const u32* __restrict__ Wh, const u32* __restrict__ EA,
        const float* __restrict__ ivm, u16* __restrict__ READ) {
    const int tid  = threadIdx.x;          // 0..127
    const int lane = tid & 63;
    const int wid  = tid >> 6;             // 0,1
    const int blk  = blockIdx.x;
    const int b    = blk >> 1;
    const int role = (blk & 1) * 2 + wid;  // 0..3
    const int base = b * SS;

    if (role < 3) {
        // ---------------- heavy wave: 64 unique columns ----------------
        const int v = role * 64 + lane;    // < 192, every lane unique

        h2v mv[25];                        // pair i = slots (2i, 2i+1)
        #pragma unroll
        for (int i = 0; i < 25; ++i) {
            mv[i].x = (_Float16)ivm[(2 * i) * VD + v];
            mv[i].y = (_Float16)ivm[(2 * i + 1) * VD + v];
        }

        int q_c = __builtin_amdgcn_readfirstlane(qd[base]);
        int q_n = __builtin_amdgcn_readfirstlane(qd[base + 1]);
        int qa0 = __builtin_amdgcn_readfirstlane(qad[base]);
        int qa1 = __builtin_amdgcn_readfirstlane(qad[base + 1]);
        u32 ea_c = EA[(size_t)qa0 * VD + v];
        u32 ea_n = EA[(size_t)qa1 * VD + v];

        u32 wb0[25], wb1[25];              // Wh row double buffer (SGPRs)
        #pragma unroll
        for (int i = 0; i < 25; ++i) wb0[i] = Wh[(size_t)q_c * WHS + i];

        for (int t = 0; t < SS; t += 2) {
            // ======== even step t: consume wb0, prefetch wb1 <- row(q_n) ====
            {
                #pragma unroll
                for (int i = 0; i < 25; ++i) wb1[i] = Wh[(size_t)q_n * WHS + i];

                int tn = t + 2; tn = (tn < SS) ? tn : (SS - 1);
                int q_nn  = __builtin_amdgcn_readfirstlane(qd[base + tn]);
                int qa_nn = __builtin_amdgcn_readfirstlane(qad[base + tn]);
                u32 ea_nn = EA[(size_t)qa_nn * VD + v];

                float rdA, rdB;
                state_step(wb0, ea_c, mv, rdA, rdB);
                READ[(size_t)(base + t) * VD + v] = f_to_bfu16(rdA + rdB);
                q_c = q_n; q_n = q_nn; ea_c = ea_n; ea_n = ea_nn;
            }
            // ======== odd step t+1: consume wb1, prefetch wb0 <- row(q_n) ===
            {
                #pragma unroll
                for (int i = 0; i < 25; ++i) wb0[i] = Wh[(size_t)q_n * WHS + i];

                int tn = t + 3; tn = (tn < SS) ? tn : (SS - 1);
                int q_nn  = __builtin_amdgcn_readfirstlane(qd[base + tn]);
                int qa_nn = __builtin_amdgcn_readfirstlane(qad[base + tn]);
                u32 ea_nn = EA[(size_t)qa_nn * VD + v];

                float rdA, rdB;
                state_step(wb1, ea_c, mv, rdA, rdB);
                READ[(size_t)(base + t + 1) * VD + v] = f_to_bfu16(rdA + rdB);
                q_c = q_n; q_n = q_nn; ea_c = ea_n; ea_n = ea_nn;
            }
        }
    } else {
        // ---------------- tail wave: v = 192..199, 8 slot-groups ----------------
        const int v8  = lane & 7;
        const int grp = lane >> 3;         // owns pairs grp*4 .. grp*4+3
        const int v   = 192 + v8;

        h2v mv4[4];
        #pragma unroll
        for (int j = 0; j < 4; ++j) {
            int p = grp * 4 + j;
            if (p < 25) {
                mv4[j].x = (_Float16)ivm[(2 * p) * VD + v];
                mv4[j].y = (_Float16)ivm[(2 * p + 1) * VD + v];
            } else {                       // padded pairs: w=0 keeps them 0
                mv4[j].x = (_Float16)0.f;
                mv4[j].y = (_Float16)0.f;
            }
        }

        int q_c = __builtin_amdgcn_readfirstlane(qd[base]);
        int q_n = __builtin_amdgcn_readfirstlane(qd[base + 1]);
        int qa0 = __builtin_amdgcn_readfirstlane(qad[base]);
        int qa1 = __builtin_amdgcn_readfirstlane(qad[base + 1]);
        u32 ea_c = EA[(size_t)qa0 * VD + v];
        u32 ea_n = EA[(size_t)qa1 * VD + v];
        u4v wq_c = *(const u4v*)(Wh + (size_t)q_c * WHS + grp * 4);
        u4v wq_n = *(const u4v*)(Wh + (size_t)q_n * WHS + grp * 4);

        for (int t = 0; t < SS; ++t) {
            int tn = t + 2; tn = (tn < SS) ? tn : (SS - 1);
            int q_nn  = __builtin_amdgcn_readfirstlane(qd[base + tn]);
            int qa_nn = __builtin_amdgcn_readfirstlane(qad[base + tn]);
            u32 ea_nn = EA[(size_t)qa_nn * VD + v];
            u4v wq_nn = *(const u4v*)(Wh + (size_t)q_nn * WHS + grp * 4);

            h2v nev2 = u32_to_h2v(__builtin_amdgcn_perm(ea_c, ea_c, 0x01000100u));
            h2v av2  = u32_to_h2v(__builtin_amdgcn_perm(ea_c, ea_c, 0x03020302u));

            float rd = 0.f;
            #pragma unroll
            for (int j = 0; j < 4; ++j) {
                h2v w2 = u32_to_h2v(wq_c[j]);
#if __has_builtin(__builtin_amdgcn_fdot2)
                rd = __builtin_amdgcn_fdot2(w2, mv4[j], rd, false);
#else
                rd = fmaf((float)w2.x, (float)mv4[j].x,
                     fmaf((float)w2.y, (float)mv4[j].y, rd));
#endif
                mv4[j] = __builtin_elementwise_fma(
                    w2, __builtin_elementwise_fma(nev2, mv4[j], av2), mv4[j]);
            }
            // reduce over the 8 slot-groups (lane stride 8)
            rd += __shfl_xor(rd, 8, 64);
            rd += __shfl_xor(rd, 16, 64);
            rd += __shfl_xor(rd, 32, 64);
            if (grp == 0)
                READ[(size_t)(base + t) * VD + v] = f_to_bfu16(rd);

            q_c = q_n; q_n = q_nn; ea_c = ea_n; ea_n = ea_nn;
            wq_c = wq_n; wq_n = wq_nn;
        }
    }
}

// ---- prediction MLP via MFMA: per wave one 16-row strip, K=224, N=64 ----
__global__ __launch_bounds__(256) void mlp_pred(
        const u16* __restrict__ RD, const int* __restrict__ qd,
        const float* __restrict__ Q1tab, const u16* __restrict__ W1s,
        const float* __restrict__ w2, const float* __restrict__ b2,
        float* __restrict__ out) {
    const int tid  = threadIdx.x;
    const int lane = tid & 63;
    const int wv   = tid >> 6;
    const int strip = blockIdx.x * 4 + wv;
    const int row0  = strip * 16;

    const int mrow = lane & 15;        // A row within strip / C-D col (feature)
    const int quad = lane >> 4;

    s8v a[7];
    {
        const u16* arow = RD + (size_t)(row0 + mrow) * VD + quad * 8;
        #pragma unroll
        for (int kt = 0; kt < 7; ++kt)
            a[kt] = *(const s8v*)(arow + kt * 32);   // k>=200 garbage * B=0
    }

    const float b2f = b2[0];
    float pf[4] = {0.f, 0.f, 0.f, 0.f};

    #pragma unroll
    for (int nt = 0; nt < 4; ++nt) {
        s8v bfr[7];
        #pragma unroll
        for (int kt = 0; kt < 7; ++kt)
            bfr[kt] = *(const s8v*)(W1s + (((nt * 7 + kt) * 64) + lane) * 8);

        f4v acc = {0.f, 0.f, 0.f, 0.f};
        #pragma unroll
        for (int kt = 0; kt < 7; ++kt)
            acc = __builtin_amdgcn_mfma_f32_16x16x32_bf16(a[kt], bfr[kt], acc, 0, 0, 0);

        const int f = nt * 16 + mrow;                  // output feature col
        const float w2f = (f < FC) ? w2[f] : 0.f;
        #pragma unroll
        for (int r = 0; r < 4; ++r) {
            int row = row0 + quad * 4 + r;
            float h = acc[r] + Q1tab[qd[row] * FC + f];
            pf[r] = fmaf(fast_tanh(h), w2f, pf[r]);
        }
    }

    #pragma unroll
    for (int r = 0; r < 4; ++r) {
        float s = pf[r];
        s += __shfl_xor(s, 1, 64);
        s += __shfl_xor(s, 2, 64);
        s += __shfl_xor(s, 4, 64);
        s += __shfl_xor(s, 8, 64);
        if (mrow == 0)
            out[row0 + quad * 4 + r] = fast_sigmoid(s + b2f);
    }
}

// ---- fallback (barrier version, f32) if workspace too small ----
__global__ void dkvmn_main(const int* __restrict__ qd, const int* __restrict__ qad,
                           const float* __restrict__ Wtab, const float* __restrict__ Q1tab,
                           const u32* __restrict__ EA,
                           const float* __restrict__ ivm,
                           const float* __restrict__ w1,
                           const float* __restrict__ w2,
                           const float* __restrict__ b2,
                           float* __restrict__ out) {
    const int tid  = threadIdx.x;
    const int b    = blockIdx.x;
    const int v    = tid;
    const int lane = tid & 63;
    const int wv   = tid >> 6;

    __shared__ alignas(16) float read_lds[4 * 52];
    __shared__ alignas(16) float part_lds[4 * 52];

    float mv[MEMN];
    if (v < VD) {
        #pragma unroll
        for (int m = 0; m < MEMN; ++m) mv[m] = ivm[m * VD + v];
    }
    float w1r[50];
    if (lane < FC) {
        #pragma unroll
        for (int i = 0; i < 50; ++i) w1r[i] = w1[(wv * 50 + i) * FC + lane];
    } else {
        #pragma unroll
        for (int i = 0; i < 50; ++i) w1r[i] = 0.f;
    }
    const float w2f = (tid < FC) ? w2[tid] : 0.f;
    const float b2f = b2[0];

    const int* qrow_i  = qd  + b * SS;
    const int* qarow_i = qad + b * SS;
    const int jchunk = v / 50;
    const int wslot  = jchunk * 52 + (v - jchunk * 50);

    for (int t = 0; t < SS; ++t) {
        const int q  = __builtin_amdgcn_readfirstlane(qrow_i[t]);
        const int qa = __builtin_amdgcn_readfirstlane(qarow_i[t]);
        const float* wrow = Wtab + q * MEMN;

        u32 ea = 0;
        if (v < VD) ea = EA[(size_t)qa * VD + v];
        float ne = h16_to_f((u16)(ea & 0xffffu));   // -e
        float av = h16_to_f((u16)(ea >> 16));       //  a

        if (v < VD) {
            float rd0 = 0.f, rd1 = 0.f;
            #pragma unroll
            for (int m = 0; m < MEMN; m += 2) {
                float wm0 = wrow[m], wm1 = wrow[m + 1];
                rd0 = fmaf(wm0, mv[m], rd0);
                mv[m] = fmaf(wm0, fmaf(ne, mv[m], av), mv[m]);
                rd1 = fmaf(wm1, mv[m + 1], rd1);
                mv[m + 1] = fmaf(wm1, fmaf(ne, mv[m + 1], av), mv[m + 1]);
            }
            read_lds[wslot] = rd0 + rd1;
        }
        __syncthreads();

        float part = 0.f;
        {
            const float* rlc = read_lds + wv * 52;
            #pragma unroll
            for (int i = 0; i < 48; i += 4) {
                float4 x = *(const float4*)(rlc + i);
                part = fmaf(x.x, w1r[i],     part);
                part = fmaf(x.y, w1r[i + 1], part);
                part = fmaf(x.z, w1r[i + 2], part);
                part = fmaf(x.w, w1r[i + 3], part);
            }
            part = fmaf(rlc[48], w1r[48], part);
            part = fmaf(rlc[49], w1r[49], part);
        }
        if (lane < FC) part_lds[wv * 52 + lane] = part;
        __syncthreads();

        if (wv == 0) {
            float pf = 0.f;
            if (lane < FC) {
                float h = part_lds[lane] + part_lds[52 + lane] +
                          part_lds[104 + lane] + part_lds[156 + lane] +
                          Q1tab[q * FC + lane];
                pf = fast_tanh(h) * w2f;
            }
            #pragma unroll
            for (int off = 32; off >= 1; off >>= 1) pf += __shfl_xor(pf, off, 64);
            if (lane == 0) out[b * SS + t] = fast_sigmoid(pf + b2f);
        }
    }
}

extern "C" void kernel_launch(void* const* d_in, const int* in_sizes, int n_in,
                              void* d_out, int out_size, void* d_ws, size_t ws_size,
                              hipStream_t stream) {
    const int* qd  = (const int*)d_in[0];
    const int* qad = (const int*)d_in[1];
    const float* qemb  = (const float*)d_in[2];
    const float* qaemb = (const float*)d_in[3];
    const float* km    = (const float*)d_in[4];
    const float* ivm   = (const float*)d_in[5];
    const float* ew    = (const float*)d_in[6];
    const float* eb    = (const float*)d_in[7];
    const float* aw    = (const float*)d_in[8];
    const float* ab    = (const float*)d_in[9];
    const float* w1    = (const float*)d_in[10];
    const float* b1    = (const float*)d_in[11];
    const float* w2    = (const float*)d_in[12];
    const float* b2    = (const float*)d_in[13];
    float* out = (float*)d_out;
    (void)in_sizes; (void)n_in; (void)out_size;

    char* ws = (char*)d_ws;
    float* Wt  = (float*)(ws);                       // 1,000,200 -> pad 1,000,448
    float* Q1  = (float*)(ws + 1000448);             // 1,000,200 -> pad 1,000,448
    u32*   EA  = (u32*)  (ws + 2000896);             // 8,000,800 -> pad 8,001,024
    u16*   W1s = (u16*)  (ws + 10001920);            // 28,672    -> pad 32,768
    u32*   Wh  = (u32*)  (ws + 10034688);            // 640,128   -> pad 640,512
    u16*   RD  = (u16*)  (ws + 10675200);            // 163,840,000
    const size_t need = 10675200ull + 163840000ull + 512ull;

    // prep: EA + Wt/Wh/Q1 + W1s + zero outputs 1..3 (one dispatch)
    prep<<<PREP_G, 256, 0, stream>>>(qemb, km, w1, b1, qaemb, ew, eb, aw, ab,
                                     Wt, Wh, Q1, EA, W1s, out + (size_t)BB * SS);

    if (ws_size >= need) {
        dkvmn_state<<<BB * 2, 128, 0, stream>>>(qd, qad, Wh, EA, ivm, RD);
        mlp_pred<<<(BB * SS) / 64, 256, 0, stream>>>(RD, qd, Q1, W1s, w2, b2, out);
    } else {
        dkvmn_main<<<BB, 256, 0, stream>>>(qd, qad, Wt, Q1, EA, ivm, w1, w2, b2, out);
    }
}